// Round 2
// baseline (15011.525 us; speedup 1.0000x reference)
//
#include <hip/hip_runtime.h>
#include <hip/hip_bf16.h>
#include <math.h>

#define NH 6
#define DKk 256
#define DVv 512
#define HIDDIM 2048
#define TT 4096
#define NBb 2
#define MTOK (NBb*TT)   // 8192

typedef __hip_bfloat16 bf16;
struct __align__(8) bh4 { bf16 x, y, z, w; };

__device__ inline float4 ld4(const float* p) { return *reinterpret_cast<const float4*>(p); }
__device__ inline float4 ld4(const bf16* p) {
    bh4 v = *reinterpret_cast<const bh4*>(p);
    return float4{ __bfloat162float(v.x), __bfloat162float(v.y),
                   __bfloat162float(v.z), __bfloat162float(v.w) };
}
__device__ inline void st4(float* p, float4 v) { *reinterpret_cast<float4*>(p) = v; }
__device__ inline void st4(bf16* p, float4 v) {
    bh4 o { __float2bfloat16(v.x), __float2bfloat16(v.y),
            __float2bfloat16(v.z), __float2bfloat16(v.w) };
    *reinterpret_cast<bh4*>(p) = o;
}

// ---------------------------------------------------------------------------
// SGEMM: C[m,n] = sum_k A[m,k] * B[n,k]  (A: MxK, B: NxK, row-major, fp32 math)
// Tile 128x128x8, 256 threads, 8x8 micro-tile. M%128==N%128==K%8==0.
// ---------------------------------------------------------------------------
template <typename TA, typename TC>
__global__ __launch_bounds__(256) void sgemm_nt(const TA* __restrict__ A,
                                                const float* __restrict__ B,
                                                TC* __restrict__ C,
                                                int M, int N, int K) {
    __shared__ float As[8][128];
    __shared__ float Bs[8][128];
    const int tid = threadIdx.x;
    const int bm = blockIdx.y * 128;
    const int bn = blockIdx.x * 128;
    const int lr = tid >> 1;
    const int lc = (tid & 1) * 4;
    const int tmr = (tid >> 4) * 8;
    const int tnr = (tid & 15) * 8;

    float acc[8][8];
#pragma unroll
    for (int i = 0; i < 8; ++i)
#pragma unroll
        for (int j = 0; j < 8; ++j) acc[i][j] = 0.f;

    const TA* Arow = A + (size_t)(bm + lr) * K + lc;
    const float* Brow = B + (size_t)(bn + lr) * K + lc;

    for (int k0 = 0; k0 < K; k0 += 8) {
        float4 av = ld4(Arow + k0);
        float4 bv = ld4(Brow + k0);
        __syncthreads();
        As[lc + 0][lr] = av.x; As[lc + 1][lr] = av.y;
        As[lc + 2][lr] = av.z; As[lc + 3][lr] = av.w;
        Bs[lc + 0][lr] = bv.x; Bs[lc + 1][lr] = bv.y;
        Bs[lc + 2][lr] = bv.z; Bs[lc + 3][lr] = bv.w;
        __syncthreads();
#pragma unroll
        for (int kk = 0; kk < 8; ++kk) {
            float af[8], bf[8];
            *reinterpret_cast<float4*>(&af[0]) = *reinterpret_cast<const float4*>(&As[kk][tmr]);
            *reinterpret_cast<float4*>(&af[4]) = *reinterpret_cast<const float4*>(&As[kk][tmr + 4]);
            *reinterpret_cast<float4*>(&bf[0]) = *reinterpret_cast<const float4*>(&Bs[kk][tnr]);
            *reinterpret_cast<float4*>(&bf[4]) = *reinterpret_cast<const float4*>(&Bs[kk][tnr + 4]);
#pragma unroll
            for (int i = 0; i < 8; ++i)
#pragma unroll
                for (int j = 0; j < 8; ++j)
                    acc[i][j] = fmaf(af[i], bf[j], acc[i][j]);
        }
    }
#pragma unroll
    for (int i = 0; i < 8; ++i) {
        TC* Cr = C + (size_t)(bm + tmr + i) * N + bn + tnr;
        float4 v0 = { acc[i][0], acc[i][1], acc[i][2], acc[i][3] };
        float4 v1 = { acc[i][4], acc[i][5], acc[i][6], acc[i][7] };
        st4(Cr, v0);
        st4(Cr + 4, v1);
    }
}

// ---------------------------------------------------------------------------
// causal depthwise conv4 + SiLU + per-head l2norm (+scale) for q/k.
// grid = MTOK*NH, block = 256 (=DK). pre/out: [MTOK, NH*DK] bf16.
// ---------------------------------------------------------------------------
__global__ __launch_bounds__(256) void convnorm_qk(const bf16* __restrict__ pre,
                                                   const float* __restrict__ cw,
                                                   bf16* __restrict__ out,
                                                   float scale) {
    const int bth = blockIdx.x;
    const int h = bth % NH;
    const int bt = bth / NH;
    const int t = bt % TT;
    const int d = threadIdx.x;
    const int c = h * DKk + d;
    const int C = NH * DKk;
    const bf16* p = pre + (size_t)bt * C + c;

    float w0 = cw[c * 4 + 0], w1 = cw[c * 4 + 1], w2 = cw[c * 4 + 2], w3 = cw[c * 4 + 3];
    float y = w3 * __bfloat162float(p[0]);
    if (t >= 1) y = fmaf(w2, __bfloat162float(p[-(ptrdiff_t)C]), y);
    if (t >= 2) y = fmaf(w1, __bfloat162float(p[-(ptrdiff_t)(2 * C)]), y);
    if (t >= 3) y = fmaf(w0, __bfloat162float(p[-(ptrdiff_t)(3 * C)]), y);
    y = y / (1.f + expf(-y));   // SiLU

    float s = y * y;
#pragma unroll
    for (int off = 32; off >= 1; off >>= 1) s += __shfl_down(s, off, 64);
    __shared__ float red[4];
    if ((threadIdx.x & 63) == 0) red[threadIdx.x >> 6] = s;
    __syncthreads();
    float tot = (red[0] + red[1]) + (red[2] + red[3]);
    out[(size_t)bt * C + c] = __float2bfloat16(y * rsqrtf(tot + 1e-6f) * scale);
}

// ---------------------------------------------------------------------------
// causal depthwise conv4 + SiLU for v. pre/out: [MTOK, NH*DV] bf16.
// ---------------------------------------------------------------------------
__global__ __launch_bounds__(256) void conv_v_kernel(const bf16* __restrict__ pre,
                                                     const float* __restrict__ cw,
                                                     bf16* __restrict__ out) {
    const int C = NH * DVv;
    int idx = blockIdx.x * 256 + threadIdx.x;
    int c = idx % C;
    int bt = idx / C;
    int t = bt % TT;
    const bf16* p = pre + (size_t)bt * C + c;
    float y = cw[c * 4 + 3] * __bfloat162float(p[0]);
    if (t >= 1) y = fmaf(cw[c * 4 + 2], __bfloat162float(p[-(ptrdiff_t)C]), y);
    if (t >= 2) y = fmaf(cw[c * 4 + 1], __bfloat162float(p[-(ptrdiff_t)(2 * C)]), y);
    if (t >= 3) y = fmaf(cw[c * 4 + 0], __bfloat162float(p[-(ptrdiff_t)(3 * C)]), y);
    out[(size_t)bt * C + c] = __float2bfloat16(y / (1.f + expf(-y)));
}

// ---------------------------------------------------------------------------
// beta = sigmoid(x@Wb.T), g = -exp(A_log)*softplus(x@Wa.T + dt_bias)
// grid = MTOK, block 256. fp32 throughout.
// ---------------------------------------------------------------------------
__global__ __launch_bounds__(256) void proj_ab(const float* __restrict__ x,
                                               const float* __restrict__ Wb,
                                               const float* __restrict__ Wa,
                                               const float* __restrict__ A_log,
                                               const float* __restrict__ dt_bias,
                                               float* __restrict__ beta,
                                               float* __restrict__ g) {
    const int bt = blockIdx.x;
    const int tid = threadIdx.x;
    const float* xr = x + (size_t)bt * HIDDIM;
    float accb[NH], acca[NH];
#pragma unroll
    for (int h = 0; h < NH; ++h) { accb[h] = 0.f; acca[h] = 0.f; }
    for (int k0 = tid; k0 < HIDDIM; k0 += 256) {
        float xv = xr[k0];
#pragma unroll
        for (int h = 0; h < NH; ++h) {
            accb[h] = fmaf(xv, Wb[h * HIDDIM + k0], accb[h]);
            acca[h] = fmaf(xv, Wa[h * HIDDIM + k0], acca[h]);
        }
    }
#pragma unroll
    for (int h = 0; h < NH; ++h) {
#pragma unroll
        for (int off = 32; off >= 1; off >>= 1) {
            accb[h] += __shfl_down(accb[h], off, 64);
            acca[h] += __shfl_down(acca[h], off, 64);
        }
    }
    __shared__ float redb[NH][4], reda[NH][4];
    int wv = tid >> 6;
    if ((tid & 63) == 0) {
#pragma unroll
        for (int h = 0; h < NH; ++h) { redb[h][wv] = accb[h]; reda[h][wv] = acca[h]; }
    }
    __syncthreads();
    if (tid < NH) {
        float sb = (redb[tid][0] + redb[tid][1]) + (redb[tid][2] + redb[tid][3]);
        float sa = (reda[tid][0] + reda[tid][1]) + (reda[tid][2] + reda[tid][3]);
        beta[(size_t)bt * NH + tid] = 1.f / (1.f + expf(-sb));
        float xg = sa + dt_bias[tid];
        float sp = fmaxf(xg, 0.f) + log1pf(expf(-fabsf(xg)));  // stable softplus
        g[(size_t)bt * NH + tid] = -expf(A_log[tid]) * sp;
    }
}

// ---------------------------------------------------------------------------
// Gated delta rule recurrence (fp32 math, bf16 I/O).
// One block per (b,h,64-col slice of DV). 4 waves: wave w owns k-rows
// [w*64,w*64+64); lane = local dv column. S in 64 VGPRs/thread.
// ---------------------------------------------------------------------------
__global__ __launch_bounds__(256) void recur_kernel(const bf16* __restrict__ q,
                                                    const bf16* __restrict__ k,
                                                    const bf16* __restrict__ v,
                                                    const float* __restrict__ g,
                                                    const float* __restrict__ beta,
                                                    bf16* __restrict__ o) {
    const int NCB = DVv / 64;  // 8
    const int cb = blockIdx.x % NCB;
    const int bh = blockIdx.x / NCB;
    const int h = bh % NH, b = bh / NH;
    const int tid = threadIdx.x;
    const int w = __builtin_amdgcn_readfirstlane(tid >> 6);
    const int lane = tid & 63;

    float S[64];
#pragma unroll
    for (int i = 0; i < 64; ++i) S[i] = 0.f;

    __shared__ float pKS[2][4][64];
    __shared__ float pO[2][4][64];

    const size_t sQK = (size_t)NH * DKk;
    const size_t sV = (size_t)NH * DVv;
    const bf16* qbp = q + (size_t)b * TT * sQK + h * DKk + w * 64;
    const bf16* kbp = k + (size_t)b * TT * sQK + h * DKk + w * 64;
    const bf16* vbp = v + (size_t)b * TT * sV + h * DVv + cb * 64 + lane;
    const float* gbp = g + (size_t)b * TT * NH + h;
    const float* bbp = beta + (size_t)b * TT * NH + h;
    bf16* obp = o + (size_t)b * TT * sV + h * DVv + cb * 64 + lane;

    for (int t = 0; t < TT; ++t) {
        const bf16* kr = kbp + (size_t)t * sQK;
        const bf16* qr = qbp + (size_t)t * sQK;
        float vv = __bfloat162float(vbp[(size_t)t * sV]);
        float gt = gbp[(size_t)t * NH];
        float bt = bbp[(size_t)t * NH];
        float eg = expf(gt);

        // pass 1: partial k·S_old
        float p0 = 0.f, p1 = 0.f, p2 = 0.f, p3 = 0.f;
#pragma unroll
        for (int i = 0; i < 64; i += 4) {
            float4 kf = ld4(kr + i);
            p0 = fmaf(kf.x, S[i + 0], p0);
            p1 = fmaf(kf.y, S[i + 1], p1);
            p2 = fmaf(kf.z, S[i + 2], p2);
            p3 = fmaf(kf.w, S[i + 3], p3);
        }
        pKS[t & 1][w][lane] = (p0 + p1) + (p2 + p3);
        __syncthreads();
        float ks = (pKS[t & 1][0][lane] + pKS[t & 1][1][lane]) +
                   (pKS[t & 1][2][lane] + pKS[t & 1][3][lane]);
        float vnew = vv - eg * ks;
        float bv = bt * vnew;

        // pass 2: S = S*eg + k*bv ; o_partial = q·S_new
        float o0 = 0.f, o1 = 0.f, o2 = 0.f, o3 = 0.f;
#pragma unroll
        for (int i = 0; i < 64; i += 4) {
            float4 kf = ld4(kr + i);
            float4 qf = ld4(qr + i);
            S[i + 0] = fmaf(S[i + 0], eg, kf.x * bv);
            S[i + 1] = fmaf(S[i + 1], eg, kf.y * bv);
            S[i + 2] = fmaf(S[i + 2], eg, kf.z * bv);
            S[i + 3] = fmaf(S[i + 3], eg, kf.w * bv);
            o0 = fmaf(qf.x, S[i + 0], o0);
            o1 = fmaf(qf.y, S[i + 1], o1);
            o2 = fmaf(qf.z, S[i + 2], o2);
            o3 = fmaf(qf.w, S[i + 3], o3);
        }
        pO[t & 1][w][lane] = (o0 + o1) + (o2 + o3);
        __syncthreads();
        if (w == 0) {
            obp[(size_t)t * sV] = __float2bfloat16(
                (pO[t & 1][0][lane] + pO[t & 1][1][lane]) +
                (pO[t & 1][2][lane] + pO[t & 1][3][lane]));
        }
    }
}

// ---------------------------------------------------------------------------
// per-head RMSNorm (eps 1e-5) * norm_w, then * silu(gate). In-place on o (bf16).
// grid = MTOK*NH, 256 threads (each handles d and d+256 of DV=512).
// ---------------------------------------------------------------------------
__global__ __launch_bounds__(256) void rmsgate_kernel(bf16* __restrict__ o,
                                                      const bf16* __restrict__ gate,
                                                      const float* __restrict__ norm_w) {
    const int bhead = blockIdx.x;
    const int d = threadIdx.x;
    bf16* op = o + (size_t)bhead * DVv;
    const bf16* gp = gate + (size_t)bhead * DVv;
    float x0 = __bfloat162float(op[d]), x1 = __bfloat162float(op[d + 256]);
    float s = x0 * x0 + x1 * x1;
#pragma unroll
    for (int off = 32; off >= 1; off >>= 1) s += __shfl_down(s, off, 64);
    __shared__ float red[4];
    if ((threadIdx.x & 63) == 0) red[threadIdx.x >> 6] = s;
    __syncthreads();
    float tot = (red[0] + red[1]) + (red[2] + red[3]);
    float r = rsqrtf(tot * (1.f / DVv) + 1e-5f);
    float g0 = __bfloat162float(gp[d]), g1 = __bfloat162float(gp[d + 256]);
    g0 = g0 / (1.f + expf(-g0));
    g1 = g1 / (1.f + expf(-g1));
    op[d]       = __float2bfloat16(x0 * r * norm_w[d] * g0);
    op[d + 256] = __float2bfloat16(x1 * r * norm_w[d + 256] * g1);
}

__global__ void fill_kernel(float* p, int n, float v) {
    int i = blockIdx.x * 256 + threadIdx.x;
    if (i < n) p[i] = v;
}

// ---------------------------------------------------------------------------
extern "C" void kernel_launch(void* const* d_in, const int* in_sizes, int n_in,
                              void* d_out, int out_size, void* d_ws, size_t ws_size,
                              hipStream_t stream) {
    const float* x       = (const float*)d_in[0];
    const float* Wq      = (const float*)d_in[1];
    const float* Wk      = (const float*)d_in[2];
    const float* Wv      = (const float*)d_in[3];
    const float* Wb      = (const float*)d_in[4];
    const float* Wa      = (const float*)d_in[5];
    const float* A_log   = (const float*)d_in[6];
    const float* dt_bias = (const float*)d_in[7];
    const float* cwq     = (const float*)d_in[8];
    const float* cwk     = (const float*)d_in[9];
    const float* cwv     = (const float*)d_in[10];
    const float* Wg      = (const float*)d_in[11];
    const float* norm_w  = (const float*)d_in[12];
    const float* Wo      = (const float*)d_in[13];
    float* out = (float*)d_out;

    // d_out doubles as scratch for q/k (bf16, 50.3MB <= 67.1MB), dead before
    // the final GEMM overwrites d_out with fp32 results.
    bf16* qb = (bf16*)d_out;                         // [8192,1536] bf16
    bf16* kb = qb + (size_t)MTOK * 1536;             // [8192,1536] bf16

    // ws: A = {preQ|preK|v|gate}, B = {preV|o}, beta/g fp32.
    const size_t elemsA = (size_t)MTOK * 3072;       // bf16 elems (50.3MB)
    const size_t elemsB = (size_t)MTOK * 3072;
    bf16* wsA   = (bf16*)d_ws;
    bf16* wsB   = wsA + elemsA;
    float* betab = (float*)(wsB + elemsB);
    float* gb    = betab + (size_t)MTOK * NH;
    size_t need = (elemsA + elemsB) * sizeof(bf16) + 2 * (size_t)MTOK * NH * sizeof(float);
    if (ws_size < need) {
        // Sentinel: make the failure mode unambiguous in the absmax report.
        fill_kernel<<<(out_size + 255) / 256, 256, 0, stream>>>(out, out_size, 1e9f);
        return;
    }

    dim3 blk(256);
    // q projection -> conv+silu+l2norm (*DK^-0.5)
    sgemm_nt<float, bf16><<<dim3(1536 / 128, MTOK / 128), blk, 0, stream>>>(x, Wq, wsA, MTOK, 1536, HIDDIM);
    convnorm_qk<<<MTOK * NH, dim3(DKk), 0, stream>>>(wsA, cwq, qb, 0.0625f);
    // k projection -> conv+silu+l2norm
    sgemm_nt<float, bf16><<<dim3(1536 / 128, MTOK / 128), blk, 0, stream>>>(x, Wk, wsA, MTOK, 1536, HIDDIM);
    convnorm_qk<<<MTOK * NH, dim3(DKk), 0, stream>>>(wsA, cwk, kb, 1.0f);
    // v projection (into B) -> conv+silu (into A)
    sgemm_nt<float, bf16><<<dim3(3072 / 128, MTOK / 128), blk, 0, stream>>>(x, Wv, wsB, MTOK, 3072, HIDDIM);
    conv_v_kernel<<<(MTOK * 3072) / 256, blk, 0, stream>>>(wsB, cwv, wsA);
    // beta / g
    proj_ab<<<MTOK, blk, 0, stream>>>(x, Wb, Wa, A_log, dt_bias, betab, gb);
    // recurrence: q,k (d_out), v (A) -> o (B, overwrites dead preV)
    recur_kernel<<<NBb * NH * (DVv / 64), blk, 0, stream>>>(qb, kb, wsA, gb, betab, wsB);
    // gate projection into A (v dead)
    sgemm_nt<float, bf16><<<dim3(3072 / 128, MTOK / 128), blk, 0, stream>>>(x, Wg, wsA, MTOK, 3072, HIDDIM);
    // rmsnorm + silu(gate), in place on o (B)
    rmsgate_kernel<<<MTOK * NH, blk, 0, stream>>>(wsB, wsA, norm_w);
    // output projection: o (bf16, B) x Wo (fp32) -> d_out fp32 (q/k dead)
    sgemm_nt<bf16, float><<<dim3(2048 / 128, MTOK / 128), blk, 0, stream>>>(wsB, Wo, out, MTOK, 2048, 3072);
}

// Round 3
// 6789.265 us; speedup vs baseline: 2.2111x; 2.2111x over previous
//
#include <hip/hip_runtime.h>
#include <hip/hip_bf16.h>
#include <math.h>

#define NH 6
#define DKk 256
#define DVv 512
#define HIDDIM 2048
#define TT 4096
#define NBb 2
#define MTOK (NBb*TT)   // 8192

typedef __hip_bfloat16 bf16;
typedef __attribute__((ext_vector_type(8))) short bf16x8;
typedef __attribute__((ext_vector_type(4))) float f32x4;

union FragU { bf16x8 v; uint2 u2[2]; uint4 u4; };
union BfBits { bf16 h; unsigned short s; };

__device__ inline float bflo(unsigned u) { return __uint_as_float(u << 16); }
__device__ inline float bfhi(unsigned u) { return __uint_as_float(u & 0xffff0000u); }

__device__ inline unsigned short bfbits(float f) {
    BfBits b; b.h = __float2bfloat16(f); return b.s;
}
__device__ inline uint4 pack8(float4 a, float4 b) {
    union { unsigned short s[8]; uint4 u; } r;
    r.s[0] = bfbits(a.x); r.s[1] = bfbits(a.y); r.s[2] = bfbits(a.z); r.s[3] = bfbits(a.w);
    r.s[4] = bfbits(b.x); r.s[5] = bfbits(b.y); r.s[6] = bfbits(b.z); r.s[7] = bfbits(b.w);
    return r.u;
}

// ---------------------------------------------------------------------------
// MFMA GEMM: C[m,n] = sum_k A[m,k]*B[n,k]; A: [M,K] (fp32 or bf16), B: [N,K]
// fp32. bf16 MFMA 16x16x32, fp32 accum. Tile 128x128xBK64, 4 waves (2x2),
// each wave 64x64 via 4x4 fragments. LDS XOR-swizzled (T2/G4).
// M%128==N%128==K%64==0.
// ---------------------------------------------------------------------------
template <typename TA, typename TC>
__global__ __launch_bounds__(256) void mfma_gemm_nt(const TA* __restrict__ A,
                                                    const float* __restrict__ B,
                                                    TC* __restrict__ C,
                                                    int M, int N, int K) {
    __shared__ __align__(16) short As[128 * 64];
    __shared__ __align__(16) short Bs[128 * 64];
    const int tid = threadIdx.x;
    const int lane = tid & 63;
    const int wid = tid >> 6;
    const int wr = wid >> 1, wc = wid & 1;
    const int bm = blockIdx.y * 128, bn = blockIdx.x * 128;

    const int srow = tid >> 1;            // staging row 0..127
    const int sks = (tid & 1) * 32;       // staging k-offset (elems)

    f32x4 acc[4][4];
#pragma unroll
    for (int i = 0; i < 4; ++i)
#pragma unroll
        for (int j = 0; j < 4; ++j) acc[i][j] = f32x4{0.f, 0.f, 0.f, 0.f};

    // byte offset in tile with XOR swizzle (applied on write AND read)
    auto swzb = [](int row, int kelem) {
        return ((row * 64 + kelem) * 2) ^ ((row & 7) << 4);
    };

    uint4 ra[4], rb[4];  // staged bf16 regs (32 elems each matrix)

    auto fetch = [&](int k0) {
        if constexpr (sizeof(TA) == 2) {
            const uint4* pa = (const uint4*)(A + (size_t)(bm + srow) * K + k0 + sks);
#pragma unroll
            for (int j = 0; j < 4; ++j) ra[j] = pa[j];
        } else {
            const float4* pa = (const float4*)(A + (size_t)(bm + srow) * K + k0 + sks);
#pragma unroll
            for (int j = 0; j < 4; ++j) ra[j] = pack8(pa[2 * j], pa[2 * j + 1]);
        }
        const float4* pb = (const float4*)(B + (size_t)(bn + srow) * K + k0 + sks);
#pragma unroll
        for (int j = 0; j < 4; ++j) rb[j] = pack8(pb[2 * j], pb[2 * j + 1]);
    };

    auto store_lds = [&]() {
#pragma unroll
        for (int j = 0; j < 4; ++j) {
            int byte = swzb(srow, sks + 8 * j);
            *(uint4*)((char*)As + byte) = ra[j];
            *(uint4*)((char*)Bs + byte) = rb[j];
        }
    };

    auto rdfrag = [&](const short* Sm, int row, int kbase) {
        FragU f;
        int ko = kbase + (lane >> 4) * 4;
        f.u2[0] = *(const uint2*)((const char*)Sm + swzb(row, ko));
        f.u2[1] = *(const uint2*)((const char*)Sm + swzb(row, ko + 16));
        return f.v;
    };

    fetch(0);
    for (int k0 = 0; k0 < K; k0 += 64) {
        __syncthreads();
        store_lds();
        __syncthreads();
        if (k0 + 64 < K) fetch(k0 + 64);
#pragma unroll
        for (int kk = 0; kk < 2; ++kk) {
            bf16x8 af[4], bfr[4];
#pragma unroll
            for (int i = 0; i < 4; ++i)
                af[i] = rdfrag(As, wr * 64 + i * 16 + (lane & 15), kk * 32);
#pragma unroll
            for (int j = 0; j < 4; ++j)
                bfr[j] = rdfrag(Bs, wc * 64 + j * 16 + (lane & 15), kk * 32);
#pragma unroll
            for (int i = 0; i < 4; ++i)
#pragma unroll
                for (int j = 0; j < 4; ++j)
                    acc[i][j] = __builtin_amdgcn_mfma_f32_16x16x32_bf16(
                        af[i], bfr[j], acc[i][j], 0, 0, 0);
        }
    }

    // epilogue: C/D layout col=lane&15, row=(lane>>4)*4+reg (m89-verified)
#pragma unroll
    for (int i = 0; i < 4; ++i)
#pragma unroll
        for (int j = 0; j < 4; ++j) {
            int row = bm + wr * 64 + i * 16 + (lane >> 4) * 4;
            int col = bn + wc * 64 + j * 16 + (lane & 15);
#pragma unroll
            for (int qi = 0; qi < 4; ++qi) {
                float vv = acc[i][j][qi];
                if constexpr (sizeof(TC) == 2)
                    C[(size_t)(row + qi) * N + col] = __float2bfloat16(vv);
                else
                    C[(size_t)(row + qi) * N + col] = vv;
            }
        }
}

// ---------------------------------------------------------------------------
// causal depthwise conv4 + SiLU + per-head l2norm (+scale) for q/k.
// ---------------------------------------------------------------------------
__global__ __launch_bounds__(256) void convnorm_qk(const bf16* __restrict__ pre,
                                                   const float* __restrict__ cw,
                                                   bf16* __restrict__ out,
                                                   float scale) {
    const int bth = blockIdx.x;
    const int h = bth % NH;
    const int bt = bth / NH;
    const int t = bt % TT;
    const int d = threadIdx.x;
    const int c = h * DKk + d;
    const int C = NH * DKk;
    const bf16* p = pre + (size_t)bt * C + c;

    float w0 = cw[c * 4 + 0], w1 = cw[c * 4 + 1], w2 = cw[c * 4 + 2], w3 = cw[c * 4 + 3];
    float y = w3 * __bfloat162float(p[0]);
    if (t >= 1) y = fmaf(w2, __bfloat162float(p[-(ptrdiff_t)C]), y);
    if (t >= 2) y = fmaf(w1, __bfloat162float(p[-(ptrdiff_t)(2 * C)]), y);
    if (t >= 3) y = fmaf(w0, __bfloat162float(p[-(ptrdiff_t)(3 * C)]), y);
    y = y / (1.f + expf(-y));   // SiLU

    float s = y * y;
#pragma unroll
    for (int off = 32; off >= 1; off >>= 1) s += __shfl_down(s, off, 64);
    __shared__ float red[4];
    if ((threadIdx.x & 63) == 0) red[threadIdx.x >> 6] = s;
    __syncthreads();
    float tot = (red[0] + red[1]) + (red[2] + red[3]);
    out[(size_t)bt * C + c] = __float2bfloat16(y * rsqrtf(tot + 1e-6f) * scale);
}

// ---------------------------------------------------------------------------
// causal depthwise conv4 + SiLU for v.
// ---------------------------------------------------------------------------
__global__ __launch_bounds__(256) void conv_v_kernel(const bf16* __restrict__ pre,
                                                     const float* __restrict__ cw,
                                                     bf16* __restrict__ out) {
    const int C = NH * DVv;
    int idx = blockIdx.x * 256 + threadIdx.x;
    int c = idx % C;
    int bt = idx / C;
    int t = bt % TT;
    const bf16* p = pre + (size_t)bt * C + c;
    float y = cw[c * 4 + 3] * __bfloat162float(p[0]);
    if (t >= 1) y = fmaf(cw[c * 4 + 2], __bfloat162float(p[-(ptrdiff_t)C]), y);
    if (t >= 2) y = fmaf(cw[c * 4 + 1], __bfloat162float(p[-(ptrdiff_t)(2 * C)]), y);
    if (t >= 3) y = fmaf(cw[c * 4 + 0], __bfloat162float(p[-(ptrdiff_t)(3 * C)]), y);
    out[(size_t)bt * C + c] = __float2bfloat16(y / (1.f + expf(-y)));
}

// ---------------------------------------------------------------------------
// beta = sigmoid(x@Wb.T), g = -exp(A_log)*softplus(x@Wa.T + dt_bias)
// ---------------------------------------------------------------------------
__global__ __launch_bounds__(256) void proj_ab(const float* __restrict__ x,
                                               const float* __restrict__ Wb,
                                               const float* __restrict__ Wa,
                                               const float* __restrict__ A_log,
                                               const float* __restrict__ dt_bias,
                                               float* __restrict__ beta,
                                               float* __restrict__ g) {
    const int bt = blockIdx.x;
    const int tid = threadIdx.x;
    const float* xr = x + (size_t)bt * HIDDIM;
    float accb[NH], acca[NH];
#pragma unroll
    for (int h = 0; h < NH; ++h) { accb[h] = 0.f; acca[h] = 0.f; }
    for (int k0 = tid; k0 < HIDDIM; k0 += 256) {
        float xv = xr[k0];
#pragma unroll
        for (int h = 0; h < NH; ++h) {
            accb[h] = fmaf(xv, Wb[h * HIDDIM + k0], accb[h]);
            acca[h] = fmaf(xv, Wa[h * HIDDIM + k0], acca[h]);
        }
    }
#pragma unroll
    for (int h = 0; h < NH; ++h) {
#pragma unroll
        for (int off = 32; off >= 1; off >>= 1) {
            accb[h] += __shfl_down(accb[h], off, 64);
            acca[h] += __shfl_down(acca[h], off, 64);
        }
    }
    __shared__ float redb[NH][4], reda[NH][4];
    int wv = tid >> 6;
    if ((tid & 63) == 0) {
#pragma unroll
        for (int h = 0; h < NH; ++h) { redb[h][wv] = accb[h]; reda[h][wv] = acca[h]; }
    }
    __syncthreads();
    if (tid < NH) {
        float sb = (redb[tid][0] + redb[tid][1]) + (redb[tid][2] + redb[tid][3]);
        float sa = (reda[tid][0] + reda[tid][1]) + (reda[tid][2] + reda[tid][3]);
        beta[(size_t)bt * NH + tid] = 1.f / (1.f + expf(-sb));
        float xg = sa + dt_bias[tid];
        float sp = fmaxf(xg, 0.f) + log1pf(expf(-fabsf(xg)));  // stable softplus
        g[(size_t)bt * NH + tid] = -expf(A_log[tid]) * sp;
    }
}

// ---------------------------------------------------------------------------
// Gated delta rule recurrence, single-wave blocks (no barriers).
// Block = 1 wave handles (b,h, 16-col slice of DV). kg=lane>>4 owns k-rows
// [kg*64,kg*64+64); dc=lane&15 is the dv column. S in 64 VGPRs/thread.
// Cross-kg reductions via 2x shfl_xor(16,32). k/v/g/beta prefetched t+1.
// ---------------------------------------------------------------------------
__global__ __launch_bounds__(64) void recur_kernel2(const bf16* __restrict__ q,
                                                    const bf16* __restrict__ k,
                                                    const bf16* __restrict__ v,
                                                    const float* __restrict__ g,
                                                    const float* __restrict__ beta,
                                                    bf16* __restrict__ o) {
    const int NCB = DVv / 16;   // 32
    const int cb = blockIdx.x % NCB;
    const int bh = blockIdx.x / NCB;
    const int h = bh % NH, b = bh / NH;
    const int lane = threadIdx.x;
    const int kg = lane >> 4;
    const int dc = lane & 15;

    float S[64];
#pragma unroll
    for (int i = 0; i < 64; ++i) S[i] = 0.f;

    const size_t sQK = (size_t)NH * DKk;
    const size_t sV  = (size_t)NH * DVv;
    const bf16* kp = k + (size_t)b * TT * sQK + h * DKk + kg * 64;
    const bf16* qp = q + (size_t)b * TT * sQK + h * DKk + kg * 64;
    const bf16* vp = v + (size_t)b * TT * sV + h * DVv + cb * 16 + dc;
    const float* gp = g + (size_t)b * TT * NH + h;
    const float* bp = beta + (size_t)b * TT * NH + h;
    bf16* op = o + (size_t)b * TT * sV + h * DVv + cb * 16 + dc;

    uint4 kA[8], kB[8];
    float vA, gA, bA, vB, gB, bB;

    auto pref = [&](uint4 (&kbuf)[8], float& vv, float& gg, float& bb, int t) {
        if (t < TT) {
            const uint4* kr = (const uint4*)(kp + (size_t)t * sQK);
#pragma unroll
            for (int j = 0; j < 8; ++j) kbuf[j] = kr[j];
            vv = __bfloat162float(vp[(size_t)t * sV]);
            gg = gp[(size_t)t * NH];
            bb = bp[(size_t)t * NH];
        }
    };

    auto body = [&](const uint4 (&kc)[8], float vv, float gg, float bb, int t) {
        // q loads issued up-front; consumed only in pass 2 (latency hides
        // under pass 1).
        const uint4* qr = (const uint4*)(qp + (size_t)t * sQK);
        uint4 qc[8];
#pragma unroll
        for (int j = 0; j < 8; ++j) qc[j] = qr[j];
        float eg = expf(gg);

        // pass 1: partial k . S_old over this lane's 64 rows
        float p0 = 0.f, p1 = 0.f, p2 = 0.f, p3 = 0.f;
#pragma unroll
        for (int c = 0; c < 8; ++c) {
            uint4 u = kc[c];
            p0 = fmaf(bflo(u.x), S[c * 8 + 0], p0);
            p1 = fmaf(bfhi(u.x), S[c * 8 + 1], p1);
            p2 = fmaf(bflo(u.y), S[c * 8 + 2], p2);
            p3 = fmaf(bfhi(u.y), S[c * 8 + 3], p3);
            p0 = fmaf(bflo(u.z), S[c * 8 + 4], p0);
            p1 = fmaf(bfhi(u.z), S[c * 8 + 5], p1);
            p2 = fmaf(bflo(u.w), S[c * 8 + 6], p2);
            p3 = fmaf(bfhi(u.w), S[c * 8 + 7], p3);
        }
        float kS = (p0 + p1) + (p2 + p3);
        kS += __shfl_xor(kS, 16, 64);
        kS += __shfl_xor(kS, 32, 64);
        float vnew = vv - eg * kS;
        float bv = bb * vnew;

        // pass 2: S = S*eg + k*bv ; o_partial = q . S_new
        float o0 = 0.f, o1 = 0.f, o2 = 0.f, o3 = 0.f;
#pragma unroll
        for (int c = 0; c < 8; ++c) {
            uint4 u = kc[c], w = qc[c];
            S[c*8+0] = fmaf(S[c*8+0], eg, bflo(u.x) * bv); o0 = fmaf(bflo(w.x), S[c*8+0], o0);
            S[c*8+1] = fmaf(S[c*8+1], eg, bfhi(u.x) * bv); o1 = fmaf(bfhi(w.x), S[c*8+1], o1);
            S[c*8+2] = fmaf(S[c*8+2], eg, bflo(u.y) * bv); o2 = fmaf(bflo(w.y), S[c*8+2], o2);
            S[c*8+3] = fmaf(S[c*8+3], eg, bfhi(u.y) * bv); o3 = fmaf(bfhi(w.y), S[c*8+3], o3);
            S[c*8+4] = fmaf(S[c*8+4], eg, bflo(u.z) * bv); o0 = fmaf(bflo(w.z), S[c*8+4], o0);
            S[c*8+5] = fmaf(S[c*8+5], eg, bfhi(u.z) * bv); o1 = fmaf(bfhi(w.z), S[c*8+5], o1);
            S[c*8+6] = fmaf(S[c*8+6], eg, bflo(u.w) * bv); o2 = fmaf(bflo(w.w), S[c*8+6], o2);
            S[c*8+7] = fmaf(S[c*8+7], eg, bfhi(u.w) * bv); o3 = fmaf(bfhi(w.w), S[c*8+7], o3);
        }
        float oo = (o0 + o1) + (o2 + o3);
        oo += __shfl_xor(oo, 16, 64);
        oo += __shfl_xor(oo, 32, 64);
        if (kg == 0) op[(size_t)t * sV] = __float2bfloat16(oo);
    };

    pref(kA, vA, gA, bA, 0);
    for (int t = 0; t < TT; t += 2) {
        pref(kB, vB, gB, bB, t + 1);
        body(kA, vA, gA, bA, t);
        pref(kA, vA, gA, bA, t + 2);
        body(kB, vB, gB, bB, t + 1);
    }
}

// ---------------------------------------------------------------------------
// per-head RMSNorm (eps 1e-5) * norm_w, then * silu(gate). In-place (bf16).
// ---------------------------------------------------------------------------
__global__ __launch_bounds__(256) void rmsgate_kernel(bf16* __restrict__ o,
                                                      const bf16* __restrict__ gate,
                                                      const float* __restrict__ norm_w) {
    const int bhead = blockIdx.x;
    const int d = threadIdx.x;
    bf16* op = o + (size_t)bhead * DVv;
    const bf16* gp = gate + (size_t)bhead * DVv;
    float x0 = __bfloat162float(op[d]), x1 = __bfloat162float(op[d + 256]);
    float s = x0 * x0 + x1 * x1;
#pragma unroll
    for (int off = 32; off >= 1; off >>= 1) s += __shfl_down(s, off, 64);
    __shared__ float red[4];
    if ((threadIdx.x & 63) == 0) red[threadIdx.x >> 6] = s;
    __syncthreads();
    float tot = (red[0] + red[1]) + (red[2] + red[3]);
    float r = rsqrtf(tot * (1.f / DVv) + 1e-5f);
    float g0 = __bfloat162float(gp[d]), g1 = __bfloat162float(gp[d + 256]);
    g0 = g0 / (1.f + expf(-g0));
    g1 = g1 / (1.f + expf(-g1));
    op[d]       = __float2bfloat16(x0 * r * norm_w[d] * g0);
    op[d + 256] = __float2bfloat16(x1 * r * norm_w[d + 256] * g1);
}

__global__ void fill_kernel(float* p, int n, float v) {
    int i = blockIdx.x * 256 + threadIdx.x;
    if (i < n) p[i] = v;
}

// ---------------------------------------------------------------------------
extern "C" void kernel_launch(void* const* d_in, const int* in_sizes, int n_in,
                              void* d_out, int out_size, void* d_ws, size_t ws_size,
                              hipStream_t stream) {
    const float* x       = (const float*)d_in[0];
    const float* Wq      = (const float*)d_in[1];
    const float* Wk      = (const float*)d_in[2];
    const float* Wv      = (const float*)d_in[3];
    const float* Wb      = (const float*)d_in[4];
    const float* Wa      = (const float*)d_in[5];
    const float* A_log   = (const float*)d_in[6];
    const float* dt_bias = (const float*)d_in[7];
    const float* cwq     = (const float*)d_in[8];
    const float* cwk     = (const float*)d_in[9];
    const float* cwv     = (const float*)d_in[10];
    const float* Wg      = (const float*)d_in[11];
    const float* norm_w  = (const float*)d_in[12];
    const float* Wo      = (const float*)d_in[13];
    float* out = (float*)d_out;

    // d_out doubles as scratch for q/k (bf16, 50.3MB <= 67.1MB), dead before
    // the final GEMM overwrites d_out with fp32 results.
    bf16* qb = (bf16*)d_out;                         // [8192,1536] bf16
    bf16* kb = qb + (size_t)MTOK * 1536;             // [8192,1536] bf16

    // ws: A = {preQ|preK|v|gate}, B = {preV|o}, beta/g fp32.
    const size_t elemsA = (size_t)MTOK * 3072;
    const size_t elemsB = (size_t)MTOK * 3072;
    bf16* wsA   = (bf16*)d_ws;
    bf16* wsB   = wsA + elemsA;
    float* betab = (float*)(wsB + elemsB);
    float* gb    = betab + (size_t)MTOK * NH;
    size_t need = (elemsA + elemsB) * sizeof(bf16) + 2 * (size_t)MTOK * NH * sizeof(float);
    if (ws_size < need) {
        fill_kernel<<<(out_size + 255) / 256, 256, 0, stream>>>(out, out_size, 1e9f);
        return;
    }

    dim3 blk(256);
    // q projection -> conv+silu+l2norm (*DK^-0.5)
    mfma_gemm_nt<float, bf16><<<dim3(12, 64), blk, 0, stream>>>(x, Wq, wsA, MTOK, 1536, HIDDIM);
    convnorm_qk<<<MTOK * NH, dim3(DKk), 0, stream>>>(wsA, cwq, qb, 0.0625f);
    // k projection -> conv+silu+l2norm
    mfma_gemm_nt<float, bf16><<<dim3(12, 64), blk, 0, stream>>>(x, Wk, wsA, MTOK, 1536, HIDDIM);
    convnorm_qk<<<MTOK * NH, dim3(DKk), 0, stream>>>(wsA, cwk, kb, 1.0f);
    // v projection (into B) -> conv+silu (into A)
    mfma_gemm_nt<float, bf16><<<dim3(24, 64), blk, 0, stream>>>(x, Wv, wsB, MTOK, 3072, HIDDIM);
    conv_v_kernel<<<(MTOK * 3072) / 256, blk, 0, stream>>>(wsB, cwv, wsA);
    // beta / g
    proj_ab<<<MTOK, blk, 0, stream>>>(x, Wb, Wa, A_log, dt_bias, betab, gb);
    // recurrence: q,k (d_out), v (A) -> o (B, overwrites dead preV)
    recur_kernel2<<<NBb * NH * (DVv / 16), dim3(64), 0, stream>>>(qb, kb, wsA, gb, betab, wsB);
    // gate projection into A (v dead)
    mfma_gemm_nt<float, bf16><<<dim3(24, 64), blk, 0, stream>>>(x, Wg, wsA, MTOK, 3072, HIDDIM);
    // rmsnorm + silu(gate), in place on o (B)
    rmsgate_kernel<<<MTOK * NH, blk, 0, stream>>>(wsB, wsA, norm_w);
    // output projection: o (bf16, B) x Wo (fp32) -> d_out fp32
    mfma_gemm_nt<bf16, float><<<dim3(16, 64), blk, 0, stream>>>(wsB, Wo, out, MTOK, 2048, 3072);
}